// Round 5
// baseline (348.721 us; speedup 1.0000x reference)
//
#include <hip/hip_runtime.h>
#include <hip/hip_bf16.h>
#include <math.h>

#define B_ 4
#define T_ 4096
#define D_ 1024
#define E_ 8
#define K_ 2
#define C_ 1537   // int(T*K/E*1.5)+1

typedef short bf16x8 __attribute__((ext_vector_type(8)));
typedef float f32x4 __attribute__((ext_vector_type(4)));

__device__ __forceinline__ unsigned short f2bf(float f) {
    union { float f; unsigned int u; } c; c.f = f;
    unsigned int u = c.u;
    unsigned int r = (u + 0x7fffu + ((u >> 16) & 1u)) >> 16;
    return (unsigned short)r;
}

// async global->LDS 16B copy (direct-to-LDS DMA, no VGPR round trip)
__device__ __forceinline__ void gl2lds16(const unsigned short* g, unsigned short* l) {
    __builtin_amdgcn_global_load_lds(
        (const __attribute__((address_space(1))) unsigned int*)g,
        (__attribute__((address_space(3))) unsigned int*)l, 16, 0, 0);
}

// ---------------------------------------------------------------------------
// Router: logits = x . Wr^T in fp64 accumulation (exact top-k ordering),
// top-2 + softmax, plus fused x -> bf16 conversion (x is fully read anyway).
// 1 wave per token, 4 tokens per block.
// ---------------------------------------------------------------------------
__global__ __launch_bounds__(256) void router_kernel(
    const float* __restrict__ x, const float* __restrict__ Wr,
    unsigned short* __restrict__ xbf, int* __restrict__ top_e,
    float* __restrict__ wbuf) {
    __shared__ float wr_s[E_ * D_];
    int tid = threadIdx.x;
    const float4* wr4 = (const float4*)Wr;
    float4* wrs4 = (float4*)wr_s;
    for (int i = tid; i < E_ * D_ / 4; i += 256) wrs4[i] = wr4[i];
    __syncthreads();

    int wave = tid >> 6, lane = tid & 63;
    int token = blockIdx.x * 4 + wave;   // 0 .. B*T-1

    const float4* xr = (const float4*)(x + (size_t)token * D_) + lane * 4;
    float xs[16];
    #pragma unroll
    for (int i = 0; i < 4; i++) {
        float4 v = xr[i];
        xs[i * 4 + 0] = v.x; xs[i * 4 + 1] = v.y;
        xs[i * 4 + 2] = v.z; xs[i * 4 + 3] = v.w;
    }

    // fused bf16 conversion of x (32 B per lane)
    unsigned short xb[16];
    #pragma unroll
    for (int i = 0; i < 16; i++) xb[i] = f2bf(xs[i]);
    uint4* dst = (uint4*)(xbf + (size_t)token * D_ + lane * 16);
    dst[0] = ((uint4*)xb)[0];
    dst[1] = ((uint4*)xb)[1];

    double acc[E_];
    #pragma unroll
    for (int e = 0; e < E_; e++) {
        const float* wp = wr_s + e * D_ + lane * 16;
        double a = 0.0;
        #pragma unroll
        for (int i = 0; i < 16; i++) a += (double)xs[i] * (double)wp[i];
        acc[e] = a;
    }
    #pragma unroll
    for (int e = 0; e < E_; e++) {
        #pragma unroll
        for (int off = 32; off > 0; off >>= 1)
            acc[e] += __shfl_down(acc[e], off, 64);
    }

    if (lane == 0) {
        int e0 = 0; double v0 = acc[0];
        #pragma unroll
        for (int e = 1; e < E_; e++) if (acc[e] > v0) { v0 = acc[e]; e0 = e; }
        int e1 = -1; double v1 = -1.0e300;
        #pragma unroll
        for (int e = 0; e < E_; e++) if (e != e0 && acc[e] > v1) { v1 = acc[e]; e1 = e; }
        double ex = exp(v1 - v0);
        float w0 = (float)(1.0 / (1.0 + ex));
        float w1 = (float)(ex / (1.0 + ex));
        top_e[token * 2 + 0] = e0;
        top_e[token * 2 + 1] = e1;
        wbuf[token * 2 + 0] = w0;
        wbuf[token * 2 + 1] = w1;
    }
}

// ---------------------------------------------------------------------------
// We[e][d][f] fp32  ->  We_t[e][f][d] bf16 (transpose so GEMM B-operand is
// k-contiguous). 64x64 tiles, 256 threads, LDS with +1 pad.
// Vectorized: float4 loads, 2x uint4 stores per thread.
// ---------------------------------------------------------------------------
__global__ __launch_bounds__(256) void wt_kernel(const float* __restrict__ We,
                                                 unsigned short* __restrict__ wtbf) {
    __shared__ unsigned short tile[64][65];
    int e = blockIdx.x >> 8;       // 256 tiles per expert
    int t = blockIdx.x & 255;
    int d0 = (t >> 4) * 64, f0 = (t & 15) * 64;
    const float* src = We + ((size_t)e * D_ + d0) * D_ + f0;
    int tid = threadIdx.x;
    #pragma unroll
    for (int i = 0; i < 4; i++) {
        int idx = tid + i * 256;           // float4 index, 0..1023
        int r = idx >> 4, c4 = (idx & 15) * 4;
        float4 v = *(const float4*)(src + (size_t)r * D_ + c4);
        tile[r][c4 + 0] = f2bf(v.x); tile[r][c4 + 1] = f2bf(v.y);
        tile[r][c4 + 2] = f2bf(v.z); tile[r][c4 + 3] = f2bf(v.w);
    }
    __syncthreads();
    unsigned short* dstp = wtbf + ((size_t)e * D_ + f0) * D_ + d0;
    int r = tid >> 2, c0 = (tid & 3) * 16;
    unsigned short vals[16];
    #pragma unroll
    for (int j = 0; j < 16; j++) vals[j] = tile[c0 + j][r];
    *(uint4*)(dstp + (size_t)r * D_ + c0)     = ((const uint4*)vals)[0];
    *(uint4*)(dstp + (size_t)r * D_ + c0 + 8) = ((const uint4*)vals)[1];
}

// ---------------------------------------------------------------------------
// Exact (t,k)-order position scan per batch. 1 block per batch.
// Produces, per (b,e): compacted slot list (slot = t*2+k) and kept count.
// ---------------------------------------------------------------------------
__global__ __launch_bounds__(256) void scan_kernel(const int* __restrict__ top_e,
                                                   int* __restrict__ list,
                                                   int* __restrict__ count) {
    int b = blockIdx.x, tid = threadIdx.x;
    const int S = T_ * K_;     // 8192 slots
    const int per = S / 256;   // 32 per thread
    __shared__ int cnt[256][E_];
    int local[E_];
    #pragma unroll
    for (int e = 0; e < E_; e++) local[e] = 0;
    const int* te = top_e + (size_t)b * S + tid * per;
    int evals[32];
    for (int i = 0; i < per; i++) { evals[i] = te[i]; local[evals[i]]++; }
    #pragma unroll
    for (int e = 0; e < E_; e++) cnt[tid][e] = local[e];
    __syncthreads();
    if (tid < E_) {
        int run = 0;
        for (int i = 0; i < 256; i++) { int v = cnt[i][tid]; cnt[i][tid] = run; run += v; }
        count[b * E_ + tid] = min(run, C_);
    }
    __syncthreads();
    int base[E_];
    #pragma unroll
    for (int e = 0; e < E_; e++) base[e] = cnt[tid][e];
    int* lst = list + (size_t)b * E_ * C_;
    for (int i = 0; i < per; i++) {
        int ev = evals[i];
        int p = base[ev]++;
        if (p < C_) lst[ev * C_ + p] = tid * per + i;
    }
}

// ---------------------------------------------------------------------------
// Grouped expert GEMM, bf16 MFMA 16x16x32, 128x128 tile, BK=32.
// A rows gathered via slot list.
// Staging: global_load_lds width=16, LINEAR (unpadded) LDS, chunk-XOR
// swizzle applied to BOTH the global source and the ds_read address
// (rule #21: both-sides-or-neither). Double-buffered, ONE barrier/K-step.
// Epilogue: atomicAdd w * row into out (unchanged from verified version).
// ---------------------------------------------------------------------------
__global__ __launch_bounds__(256) void gemm_kernel(
    const unsigned short* __restrict__ xbf, const unsigned short* __restrict__ wtbf,
    const int* __restrict__ list, const int* __restrict__ count,
    const float* __restrict__ wbuf, float* __restrict__ out) {
    int cb = blockIdx.x & 7;            // 8 col blocks (N=1024/128)
    int rb = (blockIdx.x >> 3) % 13;    // 13 row blocks (ceil(C/128))
    int pe = blockIdx.x / 104;          // (b,e) pair
    int b = pe >> 3, e = pe & 7;
    int cnt = count[pe];
    int row0 = rb * 128;
    if (row0 >= cnt) return;
    int rows = min(128, cnt - row0);

    // K-step tile: 128 rows x 32 bf16 = 8 KB each, double buffered
    __shared__ unsigned short As[2][128 * 32];
    __shared__ unsigned short Bs[2][128 * 32];
    __shared__ int slots[128];

    int tid = threadIdx.x;
    if (tid < 128) slots[tid] = (tid < rows) ? list[pe * C_ + row0 + tid] : 0;
    __syncthreads();

    // --- staging setup: wave w covers rows [w*16, w*16+16) (and +64), 4
    // chunks of 16B per row; LDS dest is linear (base + lane*16). The global
    // chunk is XOR-swizzled by (row>>1)&3 so ds_read_b128 is conflict-free.
    int w = tid >> 6, l = tid & 63;
    int rA0 = w * 16 + (l >> 2);       // 0..63
    int rA1 = rA0 + 64;                // 64..127
    int ch  = l & 3;
    int cS0 = ch ^ ((rA0 >> 1) & 3);   // swizzled source chunk
    int cS1 = ch ^ ((rA1 >> 1) & 3);
    int tA0 = slots[rA0] >> 1, tA1 = slots[rA1] >> 1;
    const unsigned short* gA0 = xbf + ((size_t)b * T_ + tA0) * D_ + cS0 * 8;
    const unsigned short* gA1 = xbf + ((size_t)b * T_ + tA1) * D_ + cS1 * 8;
    const unsigned short* gB0 = wtbf + ((size_t)e * D_ + cb * 128 + rA0) * D_ + cS0 * 8;
    const unsigned short* gB1 = wtbf + ((size_t)e * D_ + cb * 128 + rA1) * D_ + cS1 * 8;
    int sOff = w * 512 + l * 8;        // linear lane dest (elems)

    // --- MFMA fragment read addressing (swizzled to match)
    int wave = w, lane = l;
    int wm = wave >> 1, wn = wave & 1;
    int quad = lane >> 4, mrow = lane & 15;
    int qe = quad ^ ((mrow >> 1) & 3); // per-lane swizzled K-chunk
    int aRd = wm * 2048 + mrow * 32 + qe * 8;   // + i*512 per fragment row
    int bRd = wn * 2048 + mrow * 32 + qe * 8;

    f32x4 acc[4][4];
    #pragma unroll
    for (int i = 0; i < 4; i++)
        #pragma unroll
        for (int j = 0; j < 4; j++) acc[i][j] = (f32x4){0.f, 0.f, 0.f, 0.f};

#define STAGE(buf, kk) do {                                   \
        unsigned short* sA = &As[buf][sOff];                  \
        unsigned short* sB = &Bs[buf][sOff];                  \
        gl2lds16(gA0 + (kk) * 32, sA);                        \
        gl2lds16(gA1 + (kk) * 32, sA + 2048);                 \
        gl2lds16(gB0 + (kk) * 32, sB);                        \
        gl2lds16(gB1 + (kk) * 32, sB + 2048);                 \
    } while (0)

    STAGE(0, 0);
    __syncthreads();                   // vmcnt(0) drained -> buf0 ready
    int cur = 0;
    for (int kk = 0; kk < 32; kk++) {
        if (kk < 31) STAGE(cur ^ 1, kk + 1);   // async prefetch next K-step
        bf16x8 af[4], bfv[4];
        #pragma unroll
        for (int i = 0; i < 4; i++)
            af[i] = *(const bf16x8*)(&As[cur][aRd + i * 512]);
        #pragma unroll
        for (int j = 0; j < 4; j++)
            bfv[j] = *(const bf16x8*)(&Bs[cur][bRd + j * 512]);
        #pragma unroll
        for (int i = 0; i < 4; i++)
            #pragma unroll
            for (int j = 0; j < 4; j++)
                acc[i][j] = __builtin_amdgcn_mfma_f32_16x16x32_bf16(af[i], bfv[j], acc[i][j], 0, 0, 0);
        __syncthreads();               // drains vmcnt(0): next buffer ready,
        cur ^= 1;                      // and all waves done reading cur
    }
#undef STAGE

    // epilogue: C/D layout col = lane&15, row = quad*4 + r
    float* outb = out + (size_t)b * T_ * D_;
    const float* wb = wbuf + (size_t)b * T_ * 2;
    int ncolbase = cb * 128 + wn * 64 + mrow;
    #pragma unroll
    for (int i = 0; i < 4; i++) {
        #pragma unroll
        for (int r = 0; r < 4; r++) {
            int m = wm * 64 + i * 16 + quad * 4 + r;
            if (m < rows) {
                int s = slots[m];
                int t = s >> 1;
                float wgt = wb[t * 2 + (s & 1)];
                float* orow = outb + (size_t)t * D_;
                #pragma unroll
                for (int j = 0; j < 4; j++)
                    atomicAdd(orow + ncolbase + j * 16, wgt * acc[i][j][r]);
            }
        }
    }
}

// ---------------------------------------------------------------------------
extern "C" void kernel_launch(void* const* d_in, const int* in_sizes, int n_in,
                              void* d_out, int out_size, void* d_ws, size_t ws_size,
                              hipStream_t stream) {
    const float* x  = (const float*)d_in[0];   // [B,T,D]
    const float* Wr = (const float*)d_in[1];   // [E,D]
    const float* We = (const float*)d_in[2];   // [E,D,D]
    float* out = (float*)d_out;                // [B,T,D]
    char* ws = (char*)d_ws;

    // ws layout (bytes)
    unsigned short* xbf  = (unsigned short*)(ws);             // 33,554,432
    unsigned short* wtbf = (unsigned short*)(ws + 33554432);  // 16,777,216
    int*   top_e = (int*)  (ws + 50331648);                   //    131,072
    float* wbuf  = (float*)(ws + 50462720);                   //    131,072
    int*   list  = (int*)  (ws + 50593792);                   //    196,736
    int*   count = (int*)  (ws + 50790528);                   //        128

    hipMemsetAsync(d_out, 0, (size_t)out_size * sizeof(float), stream);
    router_kernel<<<dim3(B_ * T_ / 4), dim3(256), 0, stream>>>(x, Wr, xbf, top_e, wbuf);
    wt_kernel<<<dim3(E_ * 256), dim3(256), 0, stream>>>(We, wtbf);
    scan_kernel<<<dim3(B_), dim3(256), 0, stream>>>(top_e, list, count);
    gemm_kernel<<<dim3(32 * 13 * 8), dim3(256), 0, stream>>>(xbf, wtbf, list, count, wbuf, out);
}

// Round 7
// 311.493 us; speedup vs baseline: 1.1195x; 1.1195x over previous
//
#include <hip/hip_runtime.h>
#include <hip/hip_bf16.h>
#include <math.h>

#define B_ 4
#define T_ 4096
#define D_ 1024
#define E_ 8
#define K_ 2
#define C_ 1537   // int(T*K/E*1.5)+1

typedef short bf16x8 __attribute__((ext_vector_type(8)));
typedef float f32x4 __attribute__((ext_vector_type(4)));

__device__ __forceinline__ unsigned short f2bf(float f) {
    union { float f; unsigned int u; } c; c.f = f;
    unsigned int u = c.u;
    unsigned int r = (u + 0x7fffu + ((u >> 16) & 1u)) >> 16;
    return (unsigned short)r;
}

// async global->LDS 16B copy (direct-to-LDS DMA, no VGPR round trip)
__device__ __forceinline__ void gl2lds16(const unsigned short* g, unsigned short* l) {
    __builtin_amdgcn_global_load_lds(
        (const __attribute__((address_space(1))) unsigned int*)g,
        (__attribute__((address_space(3))) unsigned int*)l, 16, 0, 0);
}

// ---------------------------------------------------------------------------
// Router: logits = x . Wr^T in fp64 accumulation (exact top-k ordering),
// top-2 + softmax, plus fused x -> bf16 conversion (x is fully read anyway).
// 1 wave per token, 4 tokens per block.
// ---------------------------------------------------------------------------
__global__ __launch_bounds__(256) void router_kernel(
    const float* __restrict__ x, const float* __restrict__ Wr,
    unsigned short* __restrict__ xbf, int* __restrict__ top_e,
    float* __restrict__ wbuf) {
    __shared__ float wr_s[E_ * D_];
    int tid = threadIdx.x;
    const float4* wr4 = (const float4*)Wr;
    float4* wrs4 = (float4*)wr_s;
    for (int i = tid; i < E_ * D_ / 4; i += 256) wrs4[i] = wr4[i];
    __syncthreads();

    int wave = tid >> 6, lane = tid & 63;
    int token = blockIdx.x * 4 + wave;   // 0 .. B*T-1

    const float4* xr = (const float4*)(x + (size_t)token * D_) + lane * 4;
    float xs[16];
    #pragma unroll
    for (int i = 0; i < 4; i++) {
        float4 v = xr[i];
        xs[i * 4 + 0] = v.x; xs[i * 4 + 1] = v.y;
        xs[i * 4 + 2] = v.z; xs[i * 4 + 3] = v.w;
    }

    // fused bf16 conversion of x (32 B per lane)
    unsigned short xb[16];
    #pragma unroll
    for (int i = 0; i < 16; i++) xb[i] = f2bf(xs[i]);
    uint4* dst = (uint4*)(xbf + (size_t)token * D_ + lane * 16);
    dst[0] = ((uint4*)xb)[0];
    dst[1] = ((uint4*)xb)[1];

    double acc[E_];
    #pragma unroll
    for (int e = 0; e < E_; e++) {
        const float* wp = wr_s + e * D_ + lane * 16;
        double a = 0.0;
        #pragma unroll
        for (int i = 0; i < 16; i++) a += (double)xs[i] * (double)wp[i];
        acc[e] = a;
    }
    #pragma unroll
    for (int e = 0; e < E_; e++) {
        #pragma unroll
        for (int off = 32; off > 0; off >>= 1)
            acc[e] += __shfl_down(acc[e], off, 64);
    }

    if (lane == 0) {
        int e0 = 0; double v0 = acc[0];
        #pragma unroll
        for (int e = 1; e < E_; e++) if (acc[e] > v0) { v0 = acc[e]; e0 = e; }
        int e1 = -1; double v1 = -1.0e300;
        #pragma unroll
        for (int e = 0; e < E_; e++) if (e != e0 && acc[e] > v1) { v1 = acc[e]; e1 = e; }
        double ex = exp(v1 - v0);
        float w0 = (float)(1.0 / (1.0 + ex));
        float w1 = (float)(ex / (1.0 + ex));
        top_e[token * 2 + 0] = e0;
        top_e[token * 2 + 1] = e1;
        wbuf[token * 2 + 0] = w0;
        wbuf[token * 2 + 1] = w1;
    }
}

// ---------------------------------------------------------------------------
// We[e][d][f] fp32  ->  We_t[e][f][d] bf16 (transpose so GEMM B-operand is
// k-contiguous). 64x64 tiles, 256 threads, LDS with +1 pad.
// Vectorized: float4 loads, 2x uint4 stores per thread.
// ---------------------------------------------------------------------------
__global__ __launch_bounds__(256) void wt_kernel(const float* __restrict__ We,
                                                 unsigned short* __restrict__ wtbf) {
    __shared__ unsigned short tile[64][65];
    int e = blockIdx.x >> 8;       // 256 tiles per expert
    int t = blockIdx.x & 255;
    int d0 = (t >> 4) * 64, f0 = (t & 15) * 64;
    const float* src = We + ((size_t)e * D_ + d0) * D_ + f0;
    int tid = threadIdx.x;
    #pragma unroll
    for (int i = 0; i < 4; i++) {
        int idx = tid + i * 256;           // float4 index, 0..1023
        int r = idx >> 4, c4 = (idx & 15) * 4;
        float4 v = *(const float4*)(src + (size_t)r * D_ + c4);
        tile[r][c4 + 0] = f2bf(v.x); tile[r][c4 + 1] = f2bf(v.y);
        tile[r][c4 + 2] = f2bf(v.z); tile[r][c4 + 3] = f2bf(v.w);
    }
    __syncthreads();
    unsigned short* dstp = wtbf + ((size_t)e * D_ + f0) * D_ + d0;
    int r = tid >> 2, c0 = (tid & 3) * 16;
    unsigned short vals[16];
    #pragma unroll
    for (int j = 0; j < 16; j++) vals[j] = tile[c0 + j][r];
    *(uint4*)(dstp + (size_t)r * D_ + c0)     = ((const uint4*)vals)[0];
    *(uint4*)(dstp + (size_t)r * D_ + c0 + 8) = ((const uint4*)vals)[1];
}

// ---------------------------------------------------------------------------
// Exact (t,k)-order position scan per batch. 1 block per batch.
// Produces, per (b,e): compacted slot list (slot = t*2+k), kept count,
// and a per-slot keep flag (capacity drop marker) for the combine kernel.
// ---------------------------------------------------------------------------
__global__ __launch_bounds__(256) void scan_kernel(const int* __restrict__ top_e,
                                                   int* __restrict__ list,
                                                   int* __restrict__ count,
                                                   unsigned char* __restrict__ keep) {
    int b = blockIdx.x, tid = threadIdx.x;
    const int S = T_ * K_;     // 8192 slots
    const int per = S / 256;   // 32 per thread
    __shared__ int cnt[256][E_];
    int local[E_];
    #pragma unroll
    for (int e = 0; e < E_; e++) local[e] = 0;
    const int* te = top_e + (size_t)b * S + tid * per;
    int evals[32];
    for (int i = 0; i < per; i++) { evals[i] = te[i]; local[evals[i]]++; }
    #pragma unroll
    for (int e = 0; e < E_; e++) cnt[tid][e] = local[e];
    __syncthreads();
    if (tid < E_) {
        int run = 0;
        for (int i = 0; i < 256; i++) { int v = cnt[i][tid]; cnt[i][tid] = run; run += v; }
        count[b * E_ + tid] = min(run, C_);
    }
    __syncthreads();
    int base[E_];
    #pragma unroll
    for (int e = 0; e < E_; e++) base[e] = cnt[tid][e];
    int* lst = list + (size_t)b * E_ * C_;
    unsigned char* kp = keep + (size_t)b * S + tid * per;
    for (int i = 0; i < per; i++) {
        int ev = evals[i];
        int p = base[ev]++;
        int kept = (p < C_);
        if (kept) lst[ev * C_ + p] = tid * per + i;
        kp[i] = (unsigned char)kept;
    }
}

// ---------------------------------------------------------------------------
// Grouped expert GEMM, bf16 MFMA 16x16x32, 128x128 tile, BK=32.
// A rows gathered via slot list; global_load_lds width=16 staging with
// both-sides chunk-XOR swizzle; double-buffered, ONE barrier per K-step.
// Epilogue: if eout != nullptr, store raw expert rows (slot-indexed,
// atomic-free; weights applied in combine_kernel). Else legacy atomicAdd.
// ---------------------------------------------------------------------------
__global__ __launch_bounds__(256) void gemm_kernel(
    const unsigned short* __restrict__ xbf, const unsigned short* __restrict__ wtbf,
    const int* __restrict__ list, const int* __restrict__ count,
    const float* __restrict__ wbuf, float* __restrict__ out,
    float* __restrict__ eout) {
    int cb = blockIdx.x & 7;            // 8 col blocks (N=1024/128)
    int rb = (blockIdx.x >> 3) % 13;    // 13 row blocks (ceil(C/128))
    int pe = blockIdx.x / 104;          // (b,e) pair
    int b = pe >> 3, e = pe & 7;
    int cnt = count[pe];
    int row0 = rb * 128;
    if (row0 >= cnt) return;
    int rows = min(128, cnt - row0);

    // K-step tile: 128 rows x 32 bf16 = 8 KB each, double buffered
    __shared__ unsigned short As[2][128 * 32];
    __shared__ unsigned short Bs[2][128 * 32];
    __shared__ int slots[128];

    int tid = threadIdx.x;
    if (tid < 128) slots[tid] = (tid < rows) ? list[pe * C_ + row0 + tid] : 0;
    __syncthreads();

    // --- staging setup: wave w covers rows [w*16, w*16+16) (and +64), 4
    // chunks of 16B per row; LDS dest is linear (base + lane*16). The global
    // chunk is XOR-swizzled by (row>>1)&3 so ds_read_b128 is conflict-free.
    int w = tid >> 6, l = tid & 63;
    int rA0 = w * 16 + (l >> 2);       // 0..63
    int rA1 = rA0 + 64;                // 64..127
    int ch  = l & 3;
    int cS0 = ch ^ ((rA0 >> 1) & 3);   // swizzled source chunk
    int cS1 = ch ^ ((rA1 >> 1) & 3);
    int tA0 = slots[rA0] >> 1, tA1 = slots[rA1] >> 1;
    const unsigned short* gA0 = xbf + ((size_t)b * T_ + tA0) * D_ + cS0 * 8;
    const unsigned short* gA1 = xbf + ((size_t)b * T_ + tA1) * D_ + cS1 * 8;
    const unsigned short* gB0 = wtbf + ((size_t)e * D_ + cb * 128 + rA0) * D_ + cS0 * 8;
    const unsigned short* gB1 = wtbf + ((size_t)e * D_ + cb * 128 + rA1) * D_ + cS1 * 8;
    int sOff = w * 512 + l * 8;        // linear lane dest (elems)

    // --- MFMA fragment read addressing (swizzled to match)
    int wave = w, lane = l;
    int wm = wave >> 1, wn = wave & 1;
    int quad = lane >> 4, mrow = lane & 15;
    int qe = quad ^ ((mrow >> 1) & 3); // per-lane swizzled K-chunk
    int aRd = wm * 2048 + mrow * 32 + qe * 8;   // + i*512 per fragment row
    int bRd = wn * 2048 + mrow * 32 + qe * 8;

    f32x4 acc[4][4];
    #pragma unroll
    for (int i = 0; i < 4; i++)
        #pragma unroll
        for (int j = 0; j < 4; j++) acc[i][j] = (f32x4){0.f, 0.f, 0.f, 0.f};

#define STAGE(buf, kk) do {                                   \
        unsigned short* sA = &As[buf][sOff];                  \
        unsigned short* sB = &Bs[buf][sOff];                  \
        gl2lds16(gA0 + (kk) * 32, sA);                        \
        gl2lds16(gA1 + (kk) * 32, sA + 2048);                 \
        gl2lds16(gB0 + (kk) * 32, sB);                        \
        gl2lds16(gB1 + (kk) * 32, sB + 2048);                 \
    } while (0)

    STAGE(0, 0);
    __syncthreads();                   // vmcnt(0) drained -> buf0 ready
    int cur = 0;
    for (int kk = 0; kk < 32; kk++) {
        if (kk < 31) STAGE(cur ^ 1, kk + 1);   // async prefetch next K-step
        bf16x8 af[4], bfv[4];
        #pragma unroll
        for (int i = 0; i < 4; i++)
            af[i] = *(const bf16x8*)(&As[cur][aRd + i * 512]);
        #pragma unroll
        for (int j = 0; j < 4; j++)
            bfv[j] = *(const bf16x8*)(&Bs[cur][bRd + j * 512]);
        #pragma unroll
        for (int i = 0; i < 4; i++)
            #pragma unroll
            for (int j = 0; j < 4; j++)
                acc[i][j] = __builtin_amdgcn_mfma_f32_16x16x32_bf16(af[i], bfv[j], acc[i][j], 0, 0, 0);
        __syncthreads();               // drains vmcnt(0): next buffer ready,
        cur ^= 1;                      // and all waves done reading cur
    }
#undef STAGE

    // epilogue: C/D layout col = lane&15, row = quad*4 + r
    int ncolbase = cb * 128 + wn * 64 + mrow;
    if (eout != nullptr) {
        // atomic-free: store raw expert row into slot-indexed buffer
        float* ebase = eout + ((size_t)b * (T_ * K_)) * D_;
        #pragma unroll
        for (int i = 0; i < 4; i++) {
            #pragma unroll
            for (int r = 0; r < 4; r++) {
                int m = wm * 64 + i * 16 + quad * 4 + r;
                if (m < rows) {
                    int s = slots[m];
                    float* erow = ebase + (size_t)s * D_;
                    #pragma unroll
                    for (int j = 0; j < 4; j++)
                        erow[ncolbase + j * 16] = acc[i][j][r];
                }
            }
        }
    } else {
        // legacy path (small workspace): weighted atomicAdd into out
        float* outb = out + (size_t)b * T_ * D_;
        const float* wb = wbuf + (size_t)b * T_ * 2;
        #pragma unroll
        for (int i = 0; i < 4; i++) {
            #pragma unroll
            for (int r = 0; r < 4; r++) {
                int m = wm * 64 + i * 16 + quad * 4 + r;
                if (m < rows) {
                    int s = slots[m];
                    int t = s >> 1;
                    float wgt = wb[t * 2 + (s & 1)];
                    float* orow = outb + (size_t)t * D_;
                    #pragma unroll
                    for (int j = 0; j < 4; j++)
                        atomicAdd(orow + ncolbase + j * 16, wgt * acc[i][j][r]);
                }
            }
        }
    }
}

// ---------------------------------------------------------------------------
// Weighted combine: out[t] = k0*w0*eout[2t] + k1*w1*eout[2t+1].
// 1 wave per token, 4 tokens per block. Wave-uniform branches guard
// dropped slots (their eout rows are uninitialized garbage -> never touch).
// ---------------------------------------------------------------------------
__global__ __launch_bounds__(256) void combine_kernel(
    const float* __restrict__ eout, const float* __restrict__ wbuf,
    const unsigned char* __restrict__ keep, float* __restrict__ out) {
    int tid = threadIdx.x;
    int wave = tid >> 6, lane = tid & 63;
    int tok = blockIdx.x * 4 + wave;       // global token 0..B*T-1
    int b = tok >> 12;                     // T_ = 4096
    int tl = tok & (T_ - 1);
    size_t slot0 = (size_t)b * (T_ * K_) + (size_t)tl * 2;

    float w0 = wbuf[tok * 2 + 0];
    float w1 = wbuf[tok * 2 + 1];
    bool k0 = keep[slot0] != 0;
    bool k1 = keep[slot0 + 1] != 0;

    const float4* r0 = (const float4*)(eout + slot0 * D_) + lane * 4;
    const float4* r1 = (const float4*)(eout + (slot0 + 1) * D_) + lane * 4;
    float4* o = (float4*)(out + (size_t)tok * D_) + lane * 4;

    float4 acc[4];
    #pragma unroll
    for (int i = 0; i < 4; i++) acc[i] = make_float4(0.f, 0.f, 0.f, 0.f);
    if (k0) {
        #pragma unroll
        for (int i = 0; i < 4; i++) {
            float4 v = r0[i];
            acc[i].x += w0 * v.x; acc[i].y += w0 * v.y;
            acc[i].z += w0 * v.z; acc[i].w += w0 * v.w;
        }
    }
    if (k1) {
        #pragma unroll
        for (int i = 0; i < 4; i++) {
            float4 v = r1[i];
            acc[i].x += w1 * v.x; acc[i].y += w1 * v.y;
            acc[i].z += w1 * v.z; acc[i].w += w1 * v.w;
        }
    }
    #pragma unroll
    for (int i = 0; i < 4; i++) o[i] = acc[i];
}

// ---------------------------------------------------------------------------
extern "C" void kernel_launch(void* const* d_in, const int* in_sizes, int n_in,
                              void* d_out, int out_size, void* d_ws, size_t ws_size,
                              hipStream_t stream) {
    const float* x  = (const float*)d_in[0];   // [B,T,D]
    const float* Wr = (const float*)d_in[1];   // [E,D]
    const float* We = (const float*)d_in[2];   // [E,D,D]
    float* out = (float*)d_out;                // [B,T,D]
    char* ws = (char*)d_ws;

    // ws layout (bytes)
    unsigned short* xbf  = (unsigned short*)(ws);             // 33,554,432
    unsigned short* wtbf = (unsigned short*)(ws + 33554432);  // 16,777,216
    int*   top_e = (int*)  (ws + 50331648);                   //    131,072
    float* wbuf  = (float*)(ws + 50462720);                   //    131,072
    int*   list  = (int*)  (ws + 50593792);                   //    196,736
    int*   count = (int*)  (ws + 50790528);                   //        128
    unsigned char* keep = (unsigned char*)(ws + 50790656);    //     32,768
    const size_t EOUT_OFF = 50823424ull;                      // 16B aligned
    float* eout = (float*)(ws + EOUT_OFF);                    // 134,217,728
    const size_t NEEDED = EOUT_OFF + (size_t)B_ * T_ * K_ * D_ * 4;

    bool store_path = (ws_size >= NEEDED);

    if (!store_path)
        hipMemsetAsync(d_out, 0, (size_t)out_size * sizeof(float), stream);
    router_kernel<<<dim3(B_ * T_ / 4), dim3(256), 0, stream>>>(x, Wr, xbf, top_e, wbuf);
    wt_kernel<<<dim3(E_ * 256), dim3(256), 0, stream>>>(We, wtbf);
    scan_kernel<<<dim3(B_), dim3(256), 0, stream>>>(top_e, list, count, keep);
    gemm_kernel<<<dim3(32 * 13 * 8), dim3(256), 0, stream>>>(
        xbf, wtbf, list, count, wbuf, out, store_path ? eout : (float*)nullptr);
    if (store_path)
        combine_kernel<<<dim3(B_ * T_ / 4), dim3(256), 0, stream>>>(eout, wbuf, keep, out);
}

// Round 8
// 305.666 us; speedup vs baseline: 1.1409x; 1.0191x over previous
//
#include <hip/hip_runtime.h>
#include <hip/hip_bf16.h>
#include <math.h>

#define B_ 4
#define T_ 4096
#define D_ 1024
#define E_ 8
#define K_ 2
#define C_ 1537   // int(T*K/E*1.5)+1

typedef short bf16x8 __attribute__((ext_vector_type(8)));
typedef float f32x4 __attribute__((ext_vector_type(4)));

__device__ __forceinline__ unsigned short f2bf(float f) {
    union { float f; unsigned int u; } c; c.f = f;
    unsigned int u = c.u;
    unsigned int r = (u + 0x7fffu + ((u >> 16) & 1u)) >> 16;
    return (unsigned short)r;
}

// async global->LDS 16B copy (direct-to-LDS DMA, no VGPR round trip)
__device__ __forceinline__ void gl2lds16(const unsigned short* g, unsigned short* l) {
    __builtin_amdgcn_global_load_lds(
        (const __attribute__((address_space(1))) unsigned int*)g,
        (__attribute__((address_space(3))) unsigned int*)l, 16, 0, 0);
}

// ---------------------------------------------------------------------------
// Router: logits = x . Wr^T in fp64 accumulation (exact top-k ordering),
// top-2 + softmax, plus fused x -> bf16 conversion (x is fully read anyway).
// 1 wave per token, 4 tokens per block.
// ---------------------------------------------------------------------------
__global__ __launch_bounds__(256) void router_kernel(
    const float* __restrict__ x, const float* __restrict__ Wr,
    unsigned short* __restrict__ xbf, int* __restrict__ top_e,
    float* __restrict__ wbuf) {
    __shared__ float wr_s[E_ * D_];
    int tid = threadIdx.x;
    const float4* wr4 = (const float4*)Wr;
    float4* wrs4 = (float4*)wr_s;
    for (int i = tid; i < E_ * D_ / 4; i += 256) wrs4[i] = wr4[i];
    __syncthreads();

    int wave = tid >> 6, lane = tid & 63;
    int token = blockIdx.x * 4 + wave;   // 0 .. B*T-1

    const float4* xr = (const float4*)(x + (size_t)token * D_) + lane * 4;
    float xs[16];
    #pragma unroll
    for (int i = 0; i < 4; i++) {
        float4 v = xr[i];
        xs[i * 4 + 0] = v.x; xs[i * 4 + 1] = v.y;
        xs[i * 4 + 2] = v.z; xs[i * 4 + 3] = v.w;
    }

    // fused bf16 conversion of x (32 B per lane)
    unsigned short xb[16];
    #pragma unroll
    for (int i = 0; i < 16; i++) xb[i] = f2bf(xs[i]);
    uint4* dst = (uint4*)(xbf + (size_t)token * D_ + lane * 16);
    dst[0] = ((uint4*)xb)[0];
    dst[1] = ((uint4*)xb)[1];

    double acc[E_];
    #pragma unroll
    for (int e = 0; e < E_; e++) {
        const float* wp = wr_s + e * D_ + lane * 16;
        double a = 0.0;
        #pragma unroll
        for (int i = 0; i < 16; i++) a += (double)xs[i] * (double)wp[i];
        acc[e] = a;
    }
    #pragma unroll
    for (int e = 0; e < E_; e++) {
        #pragma unroll
        for (int off = 32; off > 0; off >>= 1)
            acc[e] += __shfl_down(acc[e], off, 64);
    }

    if (lane == 0) {
        int e0 = 0; double v0 = acc[0];
        #pragma unroll
        for (int e = 1; e < E_; e++) if (acc[e] > v0) { v0 = acc[e]; e0 = e; }
        int e1 = -1; double v1 = -1.0e300;
        #pragma unroll
        for (int e = 0; e < E_; e++) if (e != e0 && acc[e] > v1) { v1 = acc[e]; e1 = e; }
        double ex = exp(v1 - v0);
        float w0 = (float)(1.0 / (1.0 + ex));
        float w1 = (float)(ex / (1.0 + ex));
        top_e[token * 2 + 0] = e0;
        top_e[token * 2 + 1] = e1;
        wbuf[token * 2 + 0] = w0;
        wbuf[token * 2 + 1] = w1;
    }
}

// ---------------------------------------------------------------------------
// We[e][d][f] fp32  ->  We_t[e][f][d] bf16 (transpose so GEMM B-operand is
// k-contiguous). 64x64 tiles, 256 threads, LDS with +1 pad.
// Vectorized: float4 loads, 2x uint4 stores per thread.
// ---------------------------------------------------------------------------
__global__ __launch_bounds__(256) void wt_kernel(const float* __restrict__ We,
                                                 unsigned short* __restrict__ wtbf) {
    __shared__ unsigned short tile[64][65];
    int e = blockIdx.x >> 8;       // 256 tiles per expert
    int t = blockIdx.x & 255;
    int d0 = (t >> 4) * 64, f0 = (t & 15) * 64;
    const float* src = We + ((size_t)e * D_ + d0) * D_ + f0;
    int tid = threadIdx.x;
    #pragma unroll
    for (int i = 0; i < 4; i++) {
        int idx = tid + i * 256;           // float4 index, 0..1023
        int r = idx >> 4, c4 = (idx & 15) * 4;
        float4 v = *(const float4*)(src + (size_t)r * D_ + c4);
        tile[r][c4 + 0] = f2bf(v.x); tile[r][c4 + 1] = f2bf(v.y);
        tile[r][c4 + 2] = f2bf(v.z); tile[r][c4 + 3] = f2bf(v.w);
    }
    __syncthreads();
    unsigned short* dstp = wtbf + ((size_t)e * D_ + f0) * D_ + d0;
    int r = tid >> 2, c0 = (tid & 3) * 16;
    unsigned short vals[16];
    #pragma unroll
    for (int j = 0; j < 16; j++) vals[j] = tile[c0 + j][r];
    *(uint4*)(dstp + (size_t)r * D_ + c0)     = ((const uint4*)vals)[0];
    *(uint4*)(dstp + (size_t)r * D_ + c0 + 8) = ((const uint4*)vals)[1];
}

// ---------------------------------------------------------------------------
// Exact (t,k)-order position scan per batch. 1 block per batch.
// Produces, per (b,e): compacted slot list (slot = t*2+k), kept count,
// and a per-slot keep flag (capacity drop marker) for the combine kernel.
// ---------------------------------------------------------------------------
__global__ __launch_bounds__(256) void scan_kernel(const int* __restrict__ top_e,
                                                   int* __restrict__ list,
                                                   int* __restrict__ count,
                                                   unsigned char* __restrict__ keep) {
    int b = blockIdx.x, tid = threadIdx.x;
    const int S = T_ * K_;     // 8192 slots
    const int per = S / 256;   // 32 per thread
    __shared__ int cnt[256][E_];
    int local[E_];
    #pragma unroll
    for (int e = 0; e < E_; e++) local[e] = 0;
    const int* te = top_e + (size_t)b * S + tid * per;
    int evals[32];
    for (int i = 0; i < per; i++) { evals[i] = te[i]; local[evals[i]]++; }
    #pragma unroll
    for (int e = 0; e < E_; e++) cnt[tid][e] = local[e];
    __syncthreads();
    if (tid < E_) {
        int run = 0;
        for (int i = 0; i < 256; i++) { int v = cnt[i][tid]; cnt[i][tid] = run; run += v; }
        count[b * E_ + tid] = min(run, C_);
    }
    __syncthreads();
    int base[E_];
    #pragma unroll
    for (int e = 0; e < E_; e++) base[e] = cnt[tid][e];
    int* lst = list + (size_t)b * E_ * C_;
    unsigned char* kp = keep + (size_t)b * S + tid * per;
    for (int i = 0; i < per; i++) {
        int ev = evals[i];
        int p = base[ev]++;
        int kept = (p < C_);
        if (kept) lst[ev * C_ + p] = tid * per + i;
        kp[i] = (unsigned char)kept;
    }
}

// ---------------------------------------------------------------------------
// Grouped expert GEMM, bf16 MFMA 16x16x32, 128x128 tile, BK=32.
// A rows gathered via slot list; global_load_lds width=16 staging with
// both-sides chunk-XOR swizzle; double-buffered, ONE barrier per K-step.
// XCD-aware bijective blockIdx swizzle (T1): each XCD gets a contiguous
// 416-block chunk so the 8 cb-variants sharing an A-tile (and 13
// rb-variants sharing a B-tile) hit the same XCD's L2.
// Epilogue: if eout != nullptr, store raw expert rows (slot-indexed,
// atomic-free; weights applied in combine_kernel). Else legacy atomicAdd.
// ---------------------------------------------------------------------------
__global__ __launch_bounds__(256) void gemm_kernel(
    const unsigned short* __restrict__ xbf, const unsigned short* __restrict__ wtbf,
    const int* __restrict__ list, const int* __restrict__ count,
    const float* __restrict__ wbuf, float* __restrict__ out,
    float* __restrict__ eout) {
    // --- T1 XCD swizzle: nwg = 3328 = 8 * 416 (exactly divisible -> bijective)
    const int CPX = (32 * 13 * 8) / 8;      // 416 blocks per XCD chunk
    int bid = (blockIdx.x & 7) * CPX + (blockIdx.x >> 3);
    int cb = bid & 7;                   // 8 col blocks (N=1024/128)
    int rb = (bid >> 3) % 13;           // 13 row blocks (ceil(C/128))
    int pe = bid / 104;                 // (b,e) pair
    int b = pe >> 3, e = pe & 7;
    int cnt = count[pe];
    int row0 = rb * 128;
    if (row0 >= cnt) return;
    int rows = min(128, cnt - row0);

    // K-step tile: 128 rows x 32 bf16 = 8 KB each, double buffered
    __shared__ unsigned short As[2][128 * 32];
    __shared__ unsigned short Bs[2][128 * 32];
    __shared__ int slots[128];

    int tid = threadIdx.x;
    if (tid < 128) slots[tid] = (tid < rows) ? list[pe * C_ + row0 + tid] : 0;
    __syncthreads();

    // --- staging setup: wave w covers rows [w*16, w*16+16) (and +64), 4
    // chunks of 16B per row; LDS dest is linear (base + lane*16). The global
    // chunk is XOR-swizzled by (row>>1)&3 so ds_read_b128 is conflict-free.
    int w = tid >> 6, l = tid & 63;
    int rA0 = w * 16 + (l >> 2);       // 0..63
    int rA1 = rA0 + 64;                // 64..127
    int ch  = l & 3;
    int cS0 = ch ^ ((rA0 >> 1) & 3);   // swizzled source chunk
    int cS1 = ch ^ ((rA1 >> 1) & 3);
    int tA0 = slots[rA0] >> 1, tA1 = slots[rA1] >> 1;
    const unsigned short* gA0 = xbf + ((size_t)b * T_ + tA0) * D_ + cS0 * 8;
    const unsigned short* gA1 = xbf + ((size_t)b * T_ + tA1) * D_ + cS1 * 8;
    const unsigned short* gB0 = wtbf + ((size_t)e * D_ + cb * 128 + rA0) * D_ + cS0 * 8;
    const unsigned short* gB1 = wtbf + ((size_t)e * D_ + cb * 128 + rA1) * D_ + cS1 * 8;
    int sOff = w * 512 + l * 8;        // linear lane dest (elems)

    // --- MFMA fragment read addressing (swizzled to match)
    int wave = w, lane = l;
    int wm = wave >> 1, wn = wave & 1;
    int quad = lane >> 4, mrow = lane & 15;
    int qe = quad ^ ((mrow >> 1) & 3); // per-lane swizzled K-chunk
    int aRd = wm * 2048 + mrow * 32 + qe * 8;   // + i*512 per fragment row
    int bRd = wn * 2048 + mrow * 32 + qe * 8;

    f32x4 acc[4][4];
    #pragma unroll
    for (int i = 0; i < 4; i++)
        #pragma unroll
        for (int j = 0; j < 4; j++) acc[i][j] = (f32x4){0.f, 0.f, 0.f, 0.f};

#define STAGE(buf, kk) do {                                   \
        unsigned short* sA = &As[buf][sOff];                  \
        unsigned short* sB = &Bs[buf][sOff];                  \
        gl2lds16(gA0 + (kk) * 32, sA);                        \
        gl2lds16(gA1 + (kk) * 32, sA + 2048);                 \
        gl2lds16(gB0 + (kk) * 32, sB);                        \
        gl2lds16(gB1 + (kk) * 32, sB + 2048);                 \
    } while (0)

    STAGE(0, 0);
    __syncthreads();                   // vmcnt(0) drained -> buf0 ready
    int cur = 0;
    for (int kk = 0; kk < 32; kk++) {
        if (kk < 31) STAGE(cur ^ 1, kk + 1);   // async prefetch next K-step
        bf16x8 af[4], bfv[4];
        #pragma unroll
        for (int i = 0; i < 4; i++)
            af[i] = *(const bf16x8*)(&As[cur][aRd + i * 512]);
        #pragma unroll
        for (int j = 0; j < 4; j++)
            bfv[j] = *(const bf16x8*)(&Bs[cur][bRd + j * 512]);
        #pragma unroll
        for (int i = 0; i < 4; i++)
            #pragma unroll
            for (int j = 0; j < 4; j++)
                acc[i][j] = __builtin_amdgcn_mfma_f32_16x16x32_bf16(af[i], bfv[j], acc[i][j], 0, 0, 0);
        __syncthreads();               // drains vmcnt(0): next buffer ready,
        cur ^= 1;                      // and all waves done reading cur
    }
#undef STAGE

    // epilogue: C/D layout col = lane&15, row = quad*4 + r
    int ncolbase = cb * 128 + wn * 64 + mrow;
    if (eout != nullptr) {
        // atomic-free: store raw expert row into slot-indexed buffer
        float* ebase = eout + ((size_t)b * (T_ * K_)) * D_;
        #pragma unroll
        for (int i = 0; i < 4; i++) {
            #pragma unroll
            for (int r = 0; r < 4; r++) {
                int m = wm * 64 + i * 16 + quad * 4 + r;
                if (m < rows) {
                    int s = slots[m];
                    float* erow = ebase + (size_t)s * D_;
                    #pragma unroll
                    for (int j = 0; j < 4; j++)
                        erow[ncolbase + j * 16] = acc[i][j][r];
                }
            }
        }
    } else {
        // legacy path (small workspace): weighted atomicAdd into out
        float* outb = out + (size_t)b * T_ * D_;
        const float* wb = wbuf + (size_t)b * T_ * 2;
        #pragma unroll
        for (int i = 0; i < 4; i++) {
            #pragma unroll
            for (int r = 0; r < 4; r++) {
                int m = wm * 64 + i * 16 + quad * 4 + r;
                if (m < rows) {
                    int s = slots[m];
                    int t = s >> 1;
                    float wgt = wb[t * 2 + (s & 1)];
                    float* orow = outb + (size_t)t * D_;
                    #pragma unroll
                    for (int j = 0; j < 4; j++)
                        atomicAdd(orow + ncolbase + j * 16, wgt * acc[i][j][r]);
                }
            }
        }
    }
}

// ---------------------------------------------------------------------------
// Weighted combine: out[t] = k0*w0*eout[2t] + k1*w1*eout[2t+1].
// 1 wave per token, 4 tokens per block. Wave-uniform branches guard
// dropped slots (their eout rows are uninitialized garbage -> never touch).
// ---------------------------------------------------------------------------
__global__ __launch_bounds__(256) void combine_kernel(
    const float* __restrict__ eout, const float* __restrict__ wbuf,
    const unsigned char* __restrict__ keep, float* __restrict__ out) {
    int tid = threadIdx.x;
    int wave = tid >> 6, lane = tid & 63;
    int tok = blockIdx.x * 4 + wave;       // global token 0..B*T-1
    int b = tok >> 12;                     // T_ = 4096
    int tl = tok & (T_ - 1);
    size_t slot0 = (size_t)b * (T_ * K_) + (size_t)tl * 2;

    float w0 = wbuf[tok * 2 + 0];
    float w1 = wbuf[tok * 2 + 1];
    bool k0 = keep[slot0] != 0;
    bool k1 = keep[slot0 + 1] != 0;

    const float4* r0 = (const float4*)(eout + slot0 * D_) + lane * 4;
    const float4* r1 = (const float4*)(eout + (slot0 + 1) * D_) + lane * 4;
    float4* o = (float4*)(out + (size_t)tok * D_) + lane * 4;

    float4 acc[4];
    #pragma unroll
    for (int i = 0; i < 4; i++) acc[i] = make_float4(0.f, 0.f, 0.f, 0.f);
    if (k0) {
        #pragma unroll
        for (int i = 0; i < 4; i++) {
            float4 v = r0[i];
            acc[i].x += w0 * v.x; acc[i].y += w0 * v.y;
            acc[i].z += w0 * v.z; acc[i].w += w0 * v.w;
        }
    }
    if (k1) {
        #pragma unroll
        for (int i = 0; i < 4; i++) {
            float4 v = r1[i];
            acc[i].x += w1 * v.x; acc[i].y += w1 * v.y;
            acc[i].z += w1 * v.z; acc[i].w += w1 * v.w;
        }
    }
    #pragma unroll
    for (int i = 0; i < 4; i++) o[i] = acc[i];
}

// ---------------------------------------------------------------------------
extern "C" void kernel_launch(void* const* d_in, const int* in_sizes, int n_in,
                              void* d_out, int out_size, void* d_ws, size_t ws_size,
                              hipStream_t stream) {
    const float* x  = (const float*)d_in[0];   // [B,T,D]
    const float* Wr = (const float*)d_in[1];   // [E,D]
    const float* We = (const float*)d_in[2];   // [E,D,D]
    float* out = (float*)d_out;                // [B,T,D]
    char* ws = (char*)d_ws;

    // ws layout (bytes)
    unsigned short* xbf  = (unsigned short*)(ws);             // 33,554,432
    unsigned short* wtbf = (unsigned short*)(ws + 33554432);  // 16,777,216
    int*   top_e = (int*)  (ws + 50331648);                   //    131,072
    float* wbuf  = (float*)(ws + 50462720);                   //    131,072
    int*   list  = (int*)  (ws + 50593792);                   //    196,736
    int*   count = (int*)  (ws + 50790528);                   //        128
    unsigned char* keep = (unsigned char*)(ws + 50790656);    //     32,768
    const size_t EOUT_OFF = 50823424ull;                      // 16B aligned
    float* eout = (float*)(ws + EOUT_OFF);                    // 134,217,728
    const size_t NEEDED = EOUT_OFF + (size_t)B_ * T_ * K_ * D_ * 4;

    bool store_path = (ws_size >= NEEDED);

    if (!store_path)
        hipMemsetAsync(d_out, 0, (size_t)out_size * sizeof(float), stream);
    router_kernel<<<dim3(B_ * T_ / 4), dim3(256), 0, stream>>>(x, Wr, xbf, top_e, wbuf);
    wt_kernel<<<dim3(E_ * 256), dim3(256), 0, stream>>>(We, wtbf);
    scan_kernel<<<dim3(B_), dim3(256), 0, stream>>>(top_e, list, count, keep);
    gemm_kernel<<<dim3(32 * 13 * 8), dim3(256), 0, stream>>>(
        xbf, wtbf, list, count, wbuf, out, store_path ? eout : (float*)nullptr);
    if (store_path)
        combine_kernel<<<dim3(B_ * T_ / 4), dim3(256), 0, stream>>>(eout, wbuf, keep, out);
}

// Round 9
// 295.064 us; speedup vs baseline: 1.1819x; 1.0359x over previous
//
#include <hip/hip_runtime.h>
#include <hip/hip_bf16.h>
#include <math.h>

#define B_ 4
#define T_ 4096
#define D_ 1024
#define E_ 8
#define K_ 2
#define C_ 1537   // int(T*K/E*1.5)+1

typedef short bf16x8 __attribute__((ext_vector_type(8)));
typedef float f32x4 __attribute__((ext_vector_type(4)));

__device__ __forceinline__ unsigned short f2bf(float f) {
    union { float f; unsigned int u; } c; c.f = f;
    unsigned int u = c.u;
    unsigned int r = (u + 0x7fffu + ((u >> 16) & 1u)) >> 16;
    return (unsigned short)r;
}

// async global->LDS 16B copy (direct-to-LDS DMA, no VGPR round trip)
__device__ __forceinline__ void gl2lds16(const unsigned short* g, unsigned short* l) {
    __builtin_amdgcn_global_load_lds(
        (const __attribute__((address_space(1))) unsigned int*)g,
        (__attribute__((address_space(3))) unsigned int*)l, 16, 0, 0);
}

// ---------------------------------------------------------------------------
// Router: logits = x . Wr^T in fp64 accumulation (exact top-k ordering),
// top-2 + softmax, plus fused x -> bf16 conversion (x is fully read anyway).
// 1 wave per token, 4 tokens per block.
// ---------------------------------------------------------------------------
__global__ __launch_bounds__(256) void router_kernel(
    const float* __restrict__ x, const float* __restrict__ Wr,
    unsigned short* __restrict__ xbf, int* __restrict__ top_e,
    float* __restrict__ wbuf) {
    __shared__ float wr_s[E_ * D_];
    int tid = threadIdx.x;
    const float4* wr4 = (const float4*)Wr;
    float4* wrs4 = (float4*)wr_s;
    for (int i = tid; i < E_ * D_ / 4; i += 256) wrs4[i] = wr4[i];
    __syncthreads();

    int wave = tid >> 6, lane = tid & 63;
    int token = blockIdx.x * 4 + wave;   // 0 .. B*T-1

    const float4* xr = (const float4*)(x + (size_t)token * D_) + lane * 4;
    float xs[16];
    #pragma unroll
    for (int i = 0; i < 4; i++) {
        float4 v = xr[i];
        xs[i * 4 + 0] = v.x; xs[i * 4 + 1] = v.y;
        xs[i * 4 + 2] = v.z; xs[i * 4 + 3] = v.w;
    }

    // fused bf16 conversion of x (32 B per lane)
    unsigned short xb[16];
    #pragma unroll
    for (int i = 0; i < 16; i++) xb[i] = f2bf(xs[i]);
    uint4* dst = (uint4*)(xbf + (size_t)token * D_ + lane * 16);
    dst[0] = ((uint4*)xb)[0];
    dst[1] = ((uint4*)xb)[1];

    double acc[E_];
    #pragma unroll
    for (int e = 0; e < E_; e++) {
        const float* wp = wr_s + e * D_ + lane * 16;
        double a = 0.0;
        #pragma unroll
        for (int i = 0; i < 16; i++) a += (double)xs[i] * (double)wp[i];
        acc[e] = a;
    }
    #pragma unroll
    for (int e = 0; e < E_; e++) {
        #pragma unroll
        for (int off = 32; off > 0; off >>= 1)
            acc[e] += __shfl_down(acc[e], off, 64);
    }

    if (lane == 0) {
        int e0 = 0; double v0 = acc[0];
        #pragma unroll
        for (int e = 1; e < E_; e++) if (acc[e] > v0) { v0 = acc[e]; e0 = e; }
        int e1 = -1; double v1 = -1.0e300;
        #pragma unroll
        for (int e = 0; e < E_; e++) if (e != e0 && acc[e] > v1) { v1 = acc[e]; e1 = e; }
        double ex = exp(v1 - v0);
        float w0 = (float)(1.0 / (1.0 + ex));
        float w1 = (float)(ex / (1.0 + ex));
        top_e[token * 2 + 0] = e0;
        top_e[token * 2 + 1] = e1;
        wbuf[token * 2 + 0] = w0;
        wbuf[token * 2 + 1] = w1;
    }
}

// ---------------------------------------------------------------------------
// We[e][d][f] fp32  ->  We_t[e][f][d] bf16 (transpose so GEMM B-operand is
// k-contiguous). 64x64 tiles, 256 threads, LDS with +1 pad.
// Vectorized: float4 loads, 2x uint4 stores per thread.
// ---------------------------------------------------------------------------
__global__ __launch_bounds__(256) void wt_kernel(const float* __restrict__ We,
                                                 unsigned short* __restrict__ wtbf) {
    __shared__ unsigned short tile[64][65];
    int e = blockIdx.x >> 8;       // 256 tiles per expert
    int t = blockIdx.x & 255;
    int d0 = (t >> 4) * 64, f0 = (t & 15) * 64;
    const float* src = We + ((size_t)e * D_ + d0) * D_ + f0;
    int tid = threadIdx.x;
    #pragma unroll
    for (int i = 0; i < 4; i++) {
        int idx = tid + i * 256;           // float4 index, 0..1023
        int r = idx >> 4, c4 = (idx & 15) * 4;
        float4 v = *(const float4*)(src + (size_t)r * D_ + c4);
        tile[r][c4 + 0] = f2bf(v.x); tile[r][c4 + 1] = f2bf(v.y);
        tile[r][c4 + 2] = f2bf(v.z); tile[r][c4 + 3] = f2bf(v.w);
    }
    __syncthreads();
    unsigned short* dstp = wtbf + ((size_t)e * D_ + f0) * D_ + d0;
    int r = tid >> 2, c0 = (tid & 3) * 16;
    unsigned short vals[16];
    #pragma unroll
    for (int j = 0; j < 16; j++) vals[j] = tile[c0 + j][r];
    *(uint4*)(dstp + (size_t)r * D_ + c0)     = ((const uint4*)vals)[0];
    *(uint4*)(dstp + (size_t)r * D_ + c0 + 8) = ((const uint4*)vals)[1];
}

// ---------------------------------------------------------------------------
// Exact (t,k)-order position scan per batch. 1 block per batch.
// Produces, per (b,e): compacted slot list (slot = t*2+k), kept count,
// and a per-slot keep flag (capacity drop marker) for the combine kernel.
// ---------------------------------------------------------------------------
__global__ __launch_bounds__(256) void scan_kernel(const int* __restrict__ top_e,
                                                   int* __restrict__ list,
                                                   int* __restrict__ count,
                                                   unsigned char* __restrict__ keep) {
    int b = blockIdx.x, tid = threadIdx.x;
    const int S = T_ * K_;     // 8192 slots
    const int per = S / 256;   // 32 per thread
    __shared__ int cnt[256][E_];
    int local[E_];
    #pragma unroll
    for (int e = 0; e < E_; e++) local[e] = 0;
    const int* te = top_e + (size_t)b * S + tid * per;
    int evals[32];
    for (int i = 0; i < per; i++) { evals[i] = te[i]; local[evals[i]]++; }
    #pragma unroll
    for (int e = 0; e < E_; e++) cnt[tid][e] = local[e];
    __syncthreads();
    if (tid < E_) {
        int run = 0;
        for (int i = 0; i < 256; i++) { int v = cnt[i][tid]; cnt[i][tid] = run; run += v; }
        count[b * E_ + tid] = min(run, C_);
    }
    __syncthreads();
    int base[E_];
    #pragma unroll
    for (int e = 0; e < E_; e++) base[e] = cnt[tid][e];
    int* lst = list + (size_t)b * E_ * C_;
    unsigned char* kp = keep + (size_t)b * S + tid * per;
    for (int i = 0; i < per; i++) {
        int ev = evals[i];
        int p = base[ev]++;
        int kept = (p < C_);
        if (kept) lst[ev * C_ + p] = tid * per + i;
        kp[i] = (unsigned char)kept;
    }
}

// ---------------------------------------------------------------------------
// Grouped expert GEMM, bf16 MFMA 16x16x32, 128x128 tile, BK=32.
// A rows gathered via slot list; global_load_lds width=16 staging with
// both-sides chunk-XOR swizzle. XCD-aware bijective blockIdx swizzle (T1).
// K-loop: counted-vmcnt pipeline (T4) — raw s_barrier, s_waitcnt vmcnt(4)
// keeps the next tile's 4 DMA loads in flight across the barrier and under
// the MFMA phase (replaces __syncthreads' full vmcnt(0) drain).
//   pre-compute:  each wave waits its own 4 cur-loads (vmcnt(4)) then
//                 s_barrier => all cur rows resident (every wave waited).
//   end-of-iter:  raw s_barrier suffices: a wave's ds_reads are lgkm-waited
//                 before its MFMAs, so passing the barrier => reads done =>
//                 safe to overwrite the buffer next iteration.
// Epilogue: if eout != nullptr, store raw expert rows (slot-indexed,
// atomic-free; weights applied in combine_kernel). Else legacy atomicAdd.
// ---------------------------------------------------------------------------
__global__ __launch_bounds__(256) void gemm_kernel(
    const unsigned short* __restrict__ xbf, const unsigned short* __restrict__ wtbf,
    const int* __restrict__ list, const int* __restrict__ count,
    const float* __restrict__ wbuf, float* __restrict__ out,
    float* __restrict__ eout) {
    // --- T1 XCD swizzle: nwg = 3328 = 8 * 416 (exactly divisible -> bijective)
    const int CPX = (32 * 13 * 8) / 8;      // 416 blocks per XCD chunk
    int bid = (blockIdx.x & 7) * CPX + (blockIdx.x >> 3);
    int cb = bid & 7;                   // 8 col blocks (N=1024/128)
    int rb = (bid >> 3) % 13;           // 13 row blocks (ceil(C/128))
    int pe = bid / 104;                 // (b,e) pair
    int b = pe >> 3, e = pe & 7;
    int cnt = count[pe];
    int row0 = rb * 128;
    if (row0 >= cnt) return;
    int rows = min(128, cnt - row0);

    // K-step tile: 128 rows x 32 bf16 = 8 KB each, double buffered
    __shared__ unsigned short As[2][128 * 32];
    __shared__ unsigned short Bs[2][128 * 32];
    __shared__ int slots[128];

    int tid = threadIdx.x;
    if (tid < 128) slots[tid] = (tid < rows) ? list[pe * C_ + row0 + tid] : 0;
    __syncthreads();

    // --- staging setup: wave w covers rows [w*16, w*16+16) (and +64), 4
    // chunks of 16B per row; LDS dest is linear (base + lane*16). The global
    // chunk is XOR-swizzled by (row>>1)&3 so ds_read_b128 is conflict-free.
    int w = tid >> 6, l = tid & 63;
    int rA0 = w * 16 + (l >> 2);       // 0..63
    int rA1 = rA0 + 64;                // 64..127
    int ch  = l & 3;
    int cS0 = ch ^ ((rA0 >> 1) & 3);   // swizzled source chunk
    int cS1 = ch ^ ((rA1 >> 1) & 3);
    int tA0 = slots[rA0] >> 1, tA1 = slots[rA1] >> 1;
    const unsigned short* gA0 = xbf + ((size_t)b * T_ + tA0) * D_ + cS0 * 8;
    const unsigned short* gA1 = xbf + ((size_t)b * T_ + tA1) * D_ + cS1 * 8;
    const unsigned short* gB0 = wtbf + ((size_t)e * D_ + cb * 128 + rA0) * D_ + cS0 * 8;
    const unsigned short* gB1 = wtbf + ((size_t)e * D_ + cb * 128 + rA1) * D_ + cS1 * 8;
    int sOff = w * 512 + l * 8;        // linear lane dest (elems)

    // --- MFMA fragment read addressing (swizzled to match)
    int wave = w, lane = l;
    int wm = wave >> 1, wn = wave & 1;
    int quad = lane >> 4, mrow = lane & 15;
    int qe = quad ^ ((mrow >> 1) & 3); // per-lane swizzled K-chunk
    int aRd = wm * 2048 + mrow * 32 + qe * 8;   // + i*512 per fragment row
    int bRd = wn * 2048 + mrow * 32 + qe * 8;

    f32x4 acc[4][4];
    #pragma unroll
    for (int i = 0; i < 4; i++)
        #pragma unroll
        for (int j = 0; j < 4; j++) acc[i][j] = (f32x4){0.f, 0.f, 0.f, 0.f};

#define STAGE(buf, kk) do {                                   \
        unsigned short* sA = &As[buf][sOff];                  \
        unsigned short* sB = &Bs[buf][sOff];                  \
        gl2lds16(gA0 + (kk) * 32, sA);                        \
        gl2lds16(gA1 + (kk) * 32, sA + 2048);                 \
        gl2lds16(gB0 + (kk) * 32, sB);                        \
        gl2lds16(gB1 + (kk) * 32, sB + 2048);                 \
    } while (0)

    STAGE(0, 0);                       // 4 loads in flight (cur tile)
    int cur = 0;
    for (int kk = 0; kk < 32; kk++) {
        if (kk < 31) {
            STAGE(cur ^ 1, kk + 1);    // +4 loads (next tile) -> 8 in flight
            // retire the 4 OLDER loads (cur tile); next tile's 4 stay in flight
            asm volatile("s_waitcnt vmcnt(4)" ::: "memory");
        } else {
            asm volatile("s_waitcnt vmcnt(0)" ::: "memory");
        }
        __builtin_amdgcn_sched_barrier(0);
        __builtin_amdgcn_s_barrier();  // all waves waited their cur loads
        bf16x8 af[4], bfv[4];
        #pragma unroll
        for (int i = 0; i < 4; i++)
            af[i] = *(const bf16x8*)(&As[cur][aRd + i * 512]);
        #pragma unroll
        for (int j = 0; j < 4; j++)
            bfv[j] = *(const bf16x8*)(&Bs[cur][bRd + j * 512]);
        #pragma unroll
        for (int i = 0; i < 4; i++)
            #pragma unroll
            for (int j = 0; j < 4; j++)
                acc[i][j] = __builtin_amdgcn_mfma_f32_16x16x32_bf16(af[i], bfv[j], acc[i][j], 0, 0, 0);
        __builtin_amdgcn_s_barrier();  // all reads of cur done -> safe to
        cur ^= 1;                      // overwrite cur next iteration
    }
#undef STAGE

    // epilogue: C/D layout col = lane&15, row = quad*4 + r
    int ncolbase = cb * 128 + wn * 64 + mrow;
    if (eout != nullptr) {
        // atomic-free: store raw expert row into slot-indexed buffer
        float* ebase = eout + ((size_t)b * (T_ * K_)) * D_;
        #pragma unroll
        for (int i = 0; i < 4; i++) {
            #pragma unroll
            for (int r = 0; r < 4; r++) {
                int m = wm * 64 + i * 16 + quad * 4 + r;
                if (m < rows) {
                    int s = slots[m];
                    float* erow = ebase + (size_t)s * D_;
                    #pragma unroll
                    for (int j = 0; j < 4; j++)
                        erow[ncolbase + j * 16] = acc[i][j][r];
                }
            }
        }
    } else {
        // legacy path (small workspace): weighted atomicAdd into out
        float* outb = out + (size_t)b * T_ * D_;
        const float* wb = wbuf + (size_t)b * T_ * 2;
        #pragma unroll
        for (int i = 0; i < 4; i++) {
            #pragma unroll
            for (int r = 0; r < 4; r++) {
                int m = wm * 64 + i * 16 + quad * 4 + r;
                if (m < rows) {
                    int s = slots[m];
                    int t = s >> 1;
                    float wgt = wb[t * 2 + (s & 1)];
                    float* orow = outb + (size_t)t * D_;
                    #pragma unroll
                    for (int j = 0; j < 4; j++)
                        atomicAdd(orow + ncolbase + j * 16, wgt * acc[i][j][r]);
                }
            }
        }
    }
}

// ---------------------------------------------------------------------------
// Weighted combine: out[t] = k0*w0*eout[2t] + k1*w1*eout[2t+1].
// 1 wave per token, 4 tokens per block. Wave-uniform branches guard
// dropped slots (their eout rows are uninitialized garbage -> never touch).
// ---------------------------------------------------------------------------
__global__ __launch_bounds__(256) void combine_kernel(
    const float* __restrict__ eout, const float* __restrict__ wbuf,
    const unsigned char* __restrict__ keep, float* __restrict__ out) {
    int tid = threadIdx.x;
    int wave = tid >> 6, lane = tid & 63;
    int tok = blockIdx.x * 4 + wave;       // global token 0..B*T-1
    int b = tok >> 12;                     // T_ = 4096
    int tl = tok & (T_ - 1);
    size_t slot0 = (size_t)b * (T_ * K_) + (size_t)tl * 2;

    float w0 = wbuf[tok * 2 + 0];
    float w1 = wbuf[tok * 2 + 1];
    bool k0 = keep[slot0] != 0;
    bool k1 = keep[slot0 + 1] != 0;

    const float4* r0 = (const float4*)(eout + slot0 * D_) + lane * 4;
    const float4* r1 = (const float4*)(eout + (slot0 + 1) * D_) + lane * 4;
    float4* o = (float4*)(out + (size_t)tok * D_) + lane * 4;

    float4 acc[4];
    #pragma unroll
    for (int i = 0; i < 4; i++) acc[i] = make_float4(0.f, 0.f, 0.f, 0.f);
    if (k0) {
        #pragma unroll
        for (int i = 0; i < 4; i++) {
            float4 v = r0[i];
            acc[i].x += w0 * v.x; acc[i].y += w0 * v.y;
            acc[i].z += w0 * v.z; acc[i].w += w0 * v.w;
        }
    }
    if (k1) {
        #pragma unroll
        for (int i = 0; i < 4; i++) {
            float4 v = r1[i];
            acc[i].x += w1 * v.x; acc[i].y += w1 * v.y;
            acc[i].z += w1 * v.z; acc[i].w += w1 * v.w;
        }
    }
    #pragma unroll
    for (int i = 0; i < 4; i++) o[i] = acc[i];
}

// ---------------------------------------------------------------------------
extern "C" void kernel_launch(void* const* d_in, const int* in_sizes, int n_in,
                              void* d_out, int out_size, void* d_ws, size_t ws_size,
                              hipStream_t stream) {
    const float* x  = (const float*)d_in[0];   // [B,T,D]
    const float* Wr = (const float*)d_in[1];   // [E,D]
    const float* We = (const float*)d_in[2];   // [E,D,D]
    float* out = (float*)d_out;                // [B,T,D]
    char* ws = (char*)d_ws;

    // ws layout (bytes)
    unsigned short* xbf  = (unsigned short*)(ws);             // 33,554,432
    unsigned short* wtbf = (unsigned short*)(ws + 33554432);  // 16,777,216
    int*   top_e = (int*)  (ws + 50331648);                   //    131,072
    float* wbuf  = (float*)(ws + 50462720);                   //    131,072
    int*   list  = (int*)  (ws + 50593792);                   //    196,736
    int*   count = (int*)  (ws + 50790528);                   //        128
    unsigned char* keep = (unsigned char*)(ws + 50790656);    //     32,768
    const size_t EOUT_OFF = 50823424ull;                      // 16B aligned
    float* eout = (float*)(ws + EOUT_OFF);                    // 134,217,728
    const size_t NEEDED = EOUT_OFF + (size_t)B_ * T_ * K_ * D_ * 4;

    bool store_path = (ws_size >= NEEDED);

    if (!store_path)
        hipMemsetAsync(d_out, 0, (size_t)out_size * sizeof(float), stream);
    router_kernel<<<dim3(B_ * T_ / 4), dim3(256), 0, stream>>>(x, Wr, xbf, top_e, wbuf);
    wt_kernel<<<dim3(E_ * 256), dim3(256), 0, stream>>>(We, wtbf);
    scan_kernel<<<dim3(B_), dim3(256), 0, stream>>>(top_e, list, count, keep);
    gemm_kernel<<<dim3(32 * 13 * 8), dim3(256), 0, stream>>>(
        xbf, wtbf, list, count, wbuf, out, store_path ? eout : (float*)nullptr);
    if (store_path)
        combine_kernel<<<dim3(B_ * T_ / 4), dim3(256), 0, stream>>>(eout, wbuf, keep, out);
}

// Round 11
// 291.543 us; speedup vs baseline: 1.1961x; 1.0121x over previous
//
#include <hip/hip_runtime.h>
#include <hip/hip_bf16.h>
#include <math.h>

#define B_ 4
#define T_ 4096
#define D_ 1024
#define E_ 8
#define K_ 2
#define C_ 1537   // int(T*K/E*1.5)+1

typedef short bf16x8 __attribute__((ext_vector_type(8)));
typedef float f32x4 __attribute__((ext_vector_type(4)));

__device__ __forceinline__ unsigned short f2bf(float f) {
    union { float f; unsigned int u; } c; c.f = f;
    unsigned int u = c.u;
    unsigned int r = (u + 0x7fffu + ((u >> 16) & 1u)) >> 16;
    return (unsigned short)r;
}

// async global->LDS 16B copy (direct-to-LDS DMA, no VGPR round trip)
__device__ __forceinline__ void gl2lds16(const unsigned short* g, unsigned short* l) {
    __builtin_amdgcn_global_load_lds(
        (const __attribute__((address_space(1))) unsigned int*)g,
        (__attribute__((address_space(3))) unsigned int*)l, 16, 0, 0);
}

// ---------------------------------------------------------------------------
// Router: logits = x . Wr^T in fp64 accumulation (exact top-k ordering),
// top-2 + softmax, plus fused x -> bf16 conversion (x is fully read anyway).
// 1 wave per token, 4 tokens per block.
// ---------------------------------------------------------------------------
__global__ __launch_bounds__(256) void router_kernel(
    const float* __restrict__ x, const float* __restrict__ Wr,
    unsigned short* __restrict__ xbf, int* __restrict__ top_e,
    float* __restrict__ wbuf) {
    __shared__ float wr_s[E_ * D_];
    int tid = threadIdx.x;
    const float4* wr4 = (const float4*)Wr;
    float4* wrs4 = (float4*)wr_s;
    for (int i = tid; i < E_ * D_ / 4; i += 256) wrs4[i] = wr4[i];
    __syncthreads();

    int wave = tid >> 6, lane = tid & 63;
    int token = blockIdx.x * 4 + wave;   // 0 .. B*T-1

    const float4* xr = (const float4*)(x + (size_t)token * D_) + lane * 4;
    float xs[16];
    #pragma unroll
    for (int i = 0; i < 4; i++) {
        float4 v = xr[i];
        xs[i * 4 + 0] = v.x; xs[i * 4 + 1] = v.y;
        xs[i * 4 + 2] = v.z; xs[i * 4 + 3] = v.w;
    }

    // fused bf16 conversion of x (32 B per lane)
    unsigned short xb[16];
    #pragma unroll
    for (int i = 0; i < 16; i++) xb[i] = f2bf(xs[i]);
    uint4* dst = (uint4*)(xbf + (size_t)token * D_ + lane * 16);
    dst[0] = ((uint4*)xb)[0];
    dst[1] = ((uint4*)xb)[1];

    double acc[E_];
    #pragma unroll
    for (int e = 0; e < E_; e++) {
        const float* wp = wr_s + e * D_ + lane * 16;
        double a = 0.0;
        #pragma unroll
        for (int i = 0; i < 16; i++) a += (double)xs[i] * (double)wp[i];
        acc[e] = a;
    }
    #pragma unroll
    for (int e = 0; e < E_; e++) {
        #pragma unroll
        for (int off = 32; off > 0; off >>= 1)
            acc[e] += __shfl_down(acc[e], off, 64);
    }

    if (lane == 0) {
        int e0 = 0; double v0 = acc[0];
        #pragma unroll
        for (int e = 1; e < E_; e++) if (acc[e] > v0) { v0 = acc[e]; e0 = e; }
        int e1 = -1; double v1 = -1.0e300;
        #pragma unroll
        for (int e = 0; e < E_; e++) if (e != e0 && acc[e] > v1) { v1 = acc[e]; e1 = e; }
        double ex = exp(v1 - v0);
        float w0 = (float)(1.0 / (1.0 + ex));
        float w1 = (float)(ex / (1.0 + ex));
        top_e[token * 2 + 0] = e0;
        top_e[token * 2 + 1] = e1;
        wbuf[token * 2 + 0] = w0;
        wbuf[token * 2 + 1] = w1;
    }
}

// ---------------------------------------------------------------------------
// We[e][d][f] fp32  ->  We_t[e][f][d] bf16 (transpose so GEMM B-operand is
// k-contiguous). 64x64 tiles, 256 threads, LDS with +1 pad.
// Vectorized: float4 loads, 2x uint4 stores per thread.
// ---------------------------------------------------------------------------
__global__ __launch_bounds__(256) void wt_kernel(const float* __restrict__ We,
                                                 unsigned short* __restrict__ wtbf) {
    __shared__ unsigned short tile[64][65];
    int e = blockIdx.x >> 8;       // 256 tiles per expert
    int t = blockIdx.x & 255;
    int d0 = (t >> 4) * 64, f0 = (t & 15) * 64;
    const float* src = We + ((size_t)e * D_ + d0) * D_ + f0;
    int tid = threadIdx.x;
    #pragma unroll
    for (int i = 0; i < 4; i++) {
        int idx = tid + i * 256;           // float4 index, 0..1023
        int r = idx >> 4, c4 = (idx & 15) * 4;
        float4 v = *(const float4*)(src + (size_t)r * D_ + c4);
        tile[r][c4 + 0] = f2bf(v.x); tile[r][c4 + 1] = f2bf(v.y);
        tile[r][c4 + 2] = f2bf(v.z); tile[r][c4 + 3] = f2bf(v.w);
    }
    __syncthreads();
    unsigned short* dstp = wtbf + ((size_t)e * D_ + f0) * D_ + d0;
    int r = tid >> 2, c0 = (tid & 3) * 16;
    unsigned short vals[16];
    #pragma unroll
    for (int j = 0; j < 16; j++) vals[j] = tile[c0 + j][r];
    *(uint4*)(dstp + (size_t)r * D_ + c0)     = ((const uint4*)vals)[0];
    *(uint4*)(dstp + (size_t)r * D_ + c0 + 8) = ((const uint4*)vals)[1];
}

// ---------------------------------------------------------------------------
// Exact (t,k)-order position scan per batch. 1 block per batch.
// Produces, per (b,e): compacted slot list (slot = t*2+k), kept count,
// and a per-slot keep flag (capacity drop marker) for the combine kernel.
// ---------------------------------------------------------------------------
__global__ __launch_bounds__(256) void scan_kernel(const int* __restrict__ top_e,
                                                   int* __restrict__ list,
                                                   int* __restrict__ count,
                                                   unsigned char* __restrict__ keep) {
    int b = blockIdx.x, tid = threadIdx.x;
    const int S = T_ * K_;     // 8192 slots
    const int per = S / 256;   // 32 per thread
    __shared__ int cnt[256][E_];
    int local[E_];
    #pragma unroll
    for (int e = 0; e < E_; e++) local[e] = 0;
    const int* te = top_e + (size_t)b * S + tid * per;
    int evals[32];
    for (int i = 0; i < per; i++) { evals[i] = te[i]; local[evals[i]]++; }
    #pragma unroll
    for (int e = 0; e < E_; e++) cnt[tid][e] = local[e];
    __syncthreads();
    if (tid < E_) {
        int run = 0;
        for (int i = 0; i < 256; i++) { int v = cnt[i][tid]; cnt[i][tid] = run; run += v; }
        count[b * E_ + tid] = min(run, C_);
    }
    __syncthreads();
    int base[E_];
    #pragma unroll
    for (int e = 0; e < E_; e++) base[e] = cnt[tid][e];
    int* lst = list + (size_t)b * E_ * C_;
    unsigned char* kp = keep + (size_t)b * S + tid * per;
    for (int i = 0; i < per; i++) {
        int ev = evals[i];
        int p = base[ev]++;
        int kept = (p < C_);
        if (kept) lst[ev * C_ + p] = tid * per + i;
        kp[i] = (unsigned char)kept;
    }
}

// ---------------------------------------------------------------------------
// Grouped expert GEMM, bf16 MFMA 16x16x32, 128x128 tile, BK=32.
// A rows gathered via slot list; global_load_lds width=16 staging with
// both-sides chunk-XOR swizzle. XCD-aware bijective blockIdx swizzle (T1).
// K-loop: counted-vmcnt pipeline (T4) — raw s_barrier, s_waitcnt vmcnt(4)
// keeps the next tile's 4 DMA loads in flight across the barrier.
// Epilogue: if eout != nullptr, store raw expert rows as F16 (halves the
// write traffic vs f32; f16 ulp@|v|<4 = 1/256 so absmax impact ~0.002).
// Weights applied in combine_kernel. Else legacy f32 atomicAdd path.
// ---------------------------------------------------------------------------
__global__ __launch_bounds__(256) void gemm_kernel(
    const unsigned short* __restrict__ xbf, const unsigned short* __restrict__ wtbf,
    const int* __restrict__ list, const int* __restrict__ count,
    const float* __restrict__ wbuf, float* __restrict__ out,
    _Float16* __restrict__ eout) {
    // --- T1 XCD swizzle: nwg = 3328 = 8 * 416 (exactly divisible -> bijective)
    const int CPX = (32 * 13 * 8) / 8;      // 416 blocks per XCD chunk
    int bid = (blockIdx.x & 7) * CPX + (blockIdx.x >> 3);
    int cb = bid & 7;                   // 8 col blocks (N=1024/128)
    int rb = (bid >> 3) % 13;           // 13 row blocks (ceil(C/128))
    int pe = bid / 104;                 // (b,e) pair
    int b = pe >> 3, e = pe & 7;
    int cnt = count[pe];
    int row0 = rb * 128;
    if (row0 >= cnt) return;
    int rows = min(128, cnt - row0);

    // K-step tile: 128 rows x 32 bf16 = 8 KB each, double buffered
    __shared__ unsigned short As[2][128 * 32];
    __shared__ unsigned short Bs[2][128 * 32];
    __shared__ int slots[128];

    int tid = threadIdx.x;
    if (tid < 128) slots[tid] = (tid < rows) ? list[pe * C_ + row0 + tid] : 0;
    __syncthreads();

    // --- staging setup: wave w covers rows [w*16, w*16+16) (and +64), 4
    // chunks of 16B per row; LDS dest is linear (base + lane*16). The global
    // chunk is XOR-swizzled by (row>>1)&3 so ds_read_b128 is conflict-free.
    int w = tid >> 6, l = tid & 63;
    int rA0 = w * 16 + (l >> 2);       // 0..63
    int rA1 = rA0 + 64;                // 64..127
    int ch  = l & 3;
    int cS0 = ch ^ ((rA0 >> 1) & 3);   // swizzled source chunk
    int cS1 = ch ^ ((rA1 >> 1) & 3);
    int tA0 = slots[rA0] >> 1, tA1 = slots[rA1] >> 1;
    const unsigned short* gA0 = xbf + ((size_t)b * T_ + tA0) * D_ + cS0 * 8;
    const unsigned short* gA1 = xbf + ((size_t)b * T_ + tA1) * D_ + cS1 * 8;
    const unsigned short* gB0 = wtbf + ((size_t)e * D_ + cb * 128 + rA0) * D_ + cS0 * 8;
    const unsigned short* gB1 = wtbf + ((size_t)e * D_ + cb * 128 + rA1) * D_ + cS1 * 8;
    int sOff = w * 512 + l * 8;        // linear lane dest (elems)

    // --- MFMA fragment read addressing (swizzled to match)
    int wave = w, lane = l;
    int wm = wave >> 1, wn = wave & 1;
    int quad = lane >> 4, mrow = lane & 15;
    int qe = quad ^ ((mrow >> 1) & 3); // per-lane swizzled K-chunk
    int aRd = wm * 2048 + mrow * 32 + qe * 8;   // + i*512 per fragment row
    int bRd = wn * 2048 + mrow * 32 + qe * 8;

    f32x4 acc[4][4];
    #pragma unroll
    for (int i = 0; i < 4; i++)
        #pragma unroll
        for (int j = 0; j < 4; j++) acc[i][j] = (f32x4){0.f, 0.f, 0.f, 0.f};

#define STAGE(buf, kk) do {                                   \
        unsigned short* sA = &As[buf][sOff];                  \
        unsigned short* sB = &Bs[buf][sOff];                  \
        gl2lds16(gA0 + (kk) * 32, sA);                        \
        gl2lds16(gA1 + (kk) * 32, sA + 2048);                 \
        gl2lds16(gB0 + (kk) * 32, sB);                        \
        gl2lds16(gB1 + (kk) * 32, sB + 2048);                 \
    } while (0)

    STAGE(0, 0);                       // 4 loads in flight (cur tile)
    int cur = 0;
    for (int kk = 0; kk < 32; kk++) {
        if (kk < 31) {
            STAGE(cur ^ 1, kk + 1);    // +4 loads (next tile) -> 8 in flight
            // retire the 4 OLDER loads (cur tile); next tile's 4 stay in flight
            asm volatile("s_waitcnt vmcnt(4)" ::: "memory");
        } else {
            asm volatile("s_waitcnt vmcnt(0)" ::: "memory");
        }
        __builtin_amdgcn_sched_barrier(0);
        __builtin_amdgcn_s_barrier();  // all waves waited their cur loads
        bf16x8 af[4], bfv[4];
        #pragma unroll
        for (int i = 0; i < 4; i++)
            af[i] = *(const bf16x8*)(&As[cur][aRd + i * 512]);
        #pragma unroll
        for (int j = 0; j < 4; j++)
            bfv[j] = *(const bf16x8*)(&Bs[cur][bRd + j * 512]);
        #pragma unroll
        for (int i = 0; i < 4; i++)
            #pragma unroll
            for (int j = 0; j < 4; j++)
                acc[i][j] = __builtin_amdgcn_mfma_f32_16x16x32_bf16(af[i], bfv[j], acc[i][j], 0, 0, 0);
        __builtin_amdgcn_s_barrier();  // all reads of cur done -> safe to
        cur ^= 1;                      // overwrite cur next iteration
    }
#undef STAGE

    // epilogue: C/D layout col = lane&15, row = quad*4 + r
    int ncolbase = cb * 128 + wn * 64 + mrow;
    if (eout != nullptr) {
        // atomic-free: store raw expert row (f16) into slot-indexed buffer
        _Float16* ebase = eout + ((size_t)b * (T_ * K_)) * D_;
        #pragma unroll
        for (int i = 0; i < 4; i++) {
            #pragma unroll
            for (int r = 0; r < 4; r++) {
                int m = wm * 64 + i * 16 + quad * 4 + r;
                if (m < rows) {
                    int s = slots[m];
                    _Float16* erow = ebase + (size_t)s * D_;
                    #pragma unroll
                    for (int j = 0; j < 4; j++)
                        erow[ncolbase + j * 16] = (_Float16)acc[i][j][r];
                }
            }
        }
    } else {
        // legacy path (small workspace): weighted atomicAdd into out
        float* outb = out + (size_t)b * T_ * D_;
        const float* wb = wbuf + (size_t)b * T_ * 2;
        #pragma unroll
        for (int i = 0; i < 4; i++) {
            #pragma unroll
            for (int r = 0; r < 4; r++) {
                int m = wm * 64 + i * 16 + quad * 4 + r;
                if (m < rows) {
                    int s = slots[m];
                    int t = s >> 1;
                    float wgt = wb[t * 2 + (s & 1)];
                    float* orow = outb + (size_t)t * D_;
                    #pragma unroll
                    for (int j = 0; j < 4; j++)
                        atomicAdd(orow + ncolbase + j * 16, wgt * acc[i][j][r]);
                }
            }
        }
    }
}

// ---------------------------------------------------------------------------
// Weighted combine: out[t] = k0*w0*eout[2t] + k1*w1*eout[2t+1]  (eout f16).
// 1 wave per token, 4 tokens per block; 16 elems per lane (2 uint4 loads
// per slot row). Wave-uniform branches guard dropped slots (garbage rows).
// ---------------------------------------------------------------------------
__global__ __launch_bounds__(256) void combine_kernel(
    const _Float16* __restrict__ eout, const float* __restrict__ wbuf,
    const unsigned char* __restrict__ keep, float* __restrict__ out) {
    int tid = threadIdx.x;
    int wave = tid >> 6, lane = tid & 63;
    int tok = blockIdx.x * 4 + wave;       // global token 0..B*T-1
    int b = tok >> 12;                     // T_ = 4096
    int tl = tok & (T_ - 1);
    size_t slot0 = (size_t)b * (T_ * K_) + (size_t)tl * 2;

    float w0 = wbuf[tok * 2 + 0];
    float w1 = wbuf[tok * 2 + 1];
    bool k0 = keep[slot0] != 0;
    bool k1 = keep[slot0 + 1] != 0;

    const uint4* r0 = (const uint4*)(eout + slot0 * D_) + lane * 2;
    const uint4* r1 = (const uint4*)(eout + (slot0 + 1) * D_) + lane * 2;
    float4* o = (float4*)(out + (size_t)tok * D_) + lane * 4;

    float accv[16];
    #pragma unroll
    for (int i = 0; i < 16; i++) accv[i] = 0.f;
    if (k0) {
        union { uint4 v[2]; _Float16 h[16]; } u;
        u.v[0] = r0[0]; u.v[1] = r0[1];
        #pragma unroll
        for (int i = 0; i < 16; i++) accv[i] += w0 * (float)u.h[i];
    }
    if (k1) {
        union { uint4 v[2]; _Float16 h[16]; } u;
        u.v[0] = r1[0]; u.v[1] = r1[1];
        #pragma unroll
        for (int i = 0; i < 16; i++) accv[i] += w1 * (float)u.h[i];
    }
    #pragma unroll
    for (int i = 0; i < 4; i++)
        o[i] = make_float4(accv[i * 4 + 0], accv[i * 4 + 1],
                           accv[i * 4 + 2], accv[i * 4 + 3]);
}

// ---------------------------------------------------------------------------
extern "C" void kernel_launch(void* const* d_in, const int* in_sizes, int n_in,
                              void* d_out, int out_size, void* d_ws, size_t ws_size,
                              hipStream_t stream) {
    const float* x  = (const float*)d_in[0];   // [B,T,D]
    const float* Wr = (const float*)d_in[1];   // [E,D]
    const float* We = (const float*)d_in[2];   // [E,D,D]
    float* out = (float*)d_out;                // [B,T,D]
    char* ws = (char*)d_ws;

    // ws layout (bytes)
    unsigned short* xbf  = (unsigned short*)(ws);             // 33,554,432
    unsigned short* wtbf = (unsigned short*)(ws + 33554432);  // 16,777,216
    int*   top_e = (int*)  (ws + 50331648);                   //    131,072
    float* wbuf  = (float*)(ws + 50462720);                   //    131,072
    int*   list  = (int*)  (ws + 50593792);                   //    196,736
    int*   count = (int*)  (ws + 50790528);                   //        128
    unsigned char* keep = (unsigned char*)(ws + 50790656);    //     32,768
    const size_t EOUT_OFF = 50823424ull;                      // 16B aligned
    _Float16* eout = (_Float16*)(ws + EOUT_OFF);              // 67,108,864 (f16)
    const size_t NEEDED = EOUT_OFF + (size_t)B_ * T_ * K_ * D_ * 2;

    bool store_path = (ws_size >= NEEDED);

    if (!store_path)
        hipMemsetAsync(d_out, 0, (size_t)out_size * sizeof(float), stream);
    router_kernel<<<dim3(B_ * T_ / 4), dim3(256), 0, stream>>>(x, Wr, xbf, top_e, wbuf);
    wt_kernel<<<dim3(E_ * 256), dim3(256), 0, stream>>>(We, wtbf);
    scan_kernel<<<dim3(B_), dim3(256), 0, stream>>>(top_e, list, count, keep);
    gemm_kernel<<<dim3(32 * 13 * 8), dim3(256), 0, stream>>>(
        xbf, wtbf, list, count, wbuf, out, store_path ? eout : (_Float16*)nullptr);
    if (store_path)
        combine_kernel<<<dim3(B_ * T_ / 4), dim3(256), 0, stream>>>(eout, wbuf, keep, out);
}